// Round 1
// baseline (23092.596 us; speedup 1.0000x reference)
//
#include <hip/hip_runtime.h>

// ---------------------------------------------------------------------------
// VQ-VAE forward on MI355X. Round 0: correct fp32-compute baseline.
// Layouts: activations NHWC, weights pre-transposed to [tap][ci][co]
// (implicit-GEMM-friendly for future MFMA rounds). Intermediates bf16.
//
// d_out layout (fp32): x_recon (16,3,256,256) = 3145728 | z_e (16,64,64,256)
// = 16777216 | z_q same | perplexity (1).  ws usage ~220 MB.
// ---------------------------------------------------------------------------

typedef unsigned short bfraw;

__device__ __forceinline__ float bf2f(bfraw u) {
    union { unsigned int i; float f; } v; v.i = ((unsigned int)u) << 16; return v.f;
}
__device__ __forceinline__ bfraw f2bf(float f) {
    union { float f; unsigned int i; } v; v.f = f;
    unsigned int r = v.i + 0x7FFFu + ((v.i >> 16) & 1u);   // RNE
    return (bfraw)(r >> 16);
}

__device__ __forceinline__ float4 load4(const float* p) { return *(const float4*)p; }
__device__ __forceinline__ float4 load4(const bfraw* p) {
    ushort4 u = *(const ushort4*)p;
    float4 r; r.x = bf2f(u.x); r.y = bf2f(u.y); r.z = bf2f(u.z); r.w = bf2f(u.w); return r;
}
__device__ __forceinline__ float loadS(const float* p, long i) { return p[i]; }
__device__ __forceinline__ float loadS(const bfraw* p, long i) { return bf2f(p[i]); }
__device__ __forceinline__ void storeOut(float* o, long i, float4 v) { *(float4*)(o + i) = v; }
__device__ __forceinline__ void storeOut(bfraw* o, long i, float4 v) {
    ushort4 u; u.x = f2bf(v.x); u.y = f2bf(v.y); u.z = f2bf(v.z); u.w = f2bf(v.w);
    *(ushort4*)(o + i) = u;
}

// --- weight transform: OIHW (conv) / IOHW (convT) -> wt[((kh*KW+kw)*Cin+ci)*Cout+co]
__global__ void wt_kernel(const float* __restrict__ w, float* __restrict__ wt,
                          int Cout, int Cin, int KH, int KW, int transposed) {
    int n = Cout * Cin * KH * KW;
    for (int i = blockIdx.x * blockDim.x + threadIdx.x; i < n; i += gridDim.x * blockDim.x) {
        int co = i % Cout; int t = i / Cout;
        int ci = t % Cin;  int tap = t / Cin;
        int kw = tap % KW; int kh = tap / KW;
        float v = transposed ? w[(((long)ci * Cout + co) * KH + kh) * KW + kw]
                             : w[(((long)co * Cin + ci) * KH + kh) * KW + kw];
        wt[i] = v;
    }
}

// --- emb row norms: ||e_k||^2 (512 blocks x 64 threads)
__global__ void embsq_kernel(const float* __restrict__ emb, float* __restrict__ esq) {
    int k = blockIdx.x, lane = threadIdx.x;
    float s = 0.f;
    for (int d = lane; d < 256; d += 64) { float v = emb[k * 256 + d]; s += v * v; }
    for (int o = 32; o; o >>= 1) s += __shfl_down(s, o, 64);
    if (lane == 0) esq[k] = s;
}

// --- emb transpose: embT[d*512+k] = emb[k*256+d]
__global__ void embT_kernel(const float* __restrict__ emb, float* __restrict__ embT) {
    int i = blockIdx.x * blockDim.x + threadIdx.x;
    if (i < 512 * 256) { int k = i >> 8; int d = i & 255; embT[d * 512 + k] = emb[i]; }
}

// --- generic direct conv / convT, NHWC out [pos*Cout+co], 4 output channels per lane
template <typename TIN, typename TOUT, bool RELU, bool TR>
__global__ __launch_bounds__(256) void conv_kernel(
    const TIN* __restrict__ in, const float* __restrict__ wt,
    const float* __restrict__ bias, TOUT* __restrict__ out,
    int NPOS, int Hin, int Win, int Cin, int Hout, int Wout, int Cout,
    int KH, int KW, int stride, int pad,
    long sN, long sH, long sW, long sC) {
    int lpp = Cout >> 2;                       // lanes per position
    int g   = threadIdx.x / lpp;
    int co  = (threadIdx.x % lpp) << 2;
    int G   = blockDim.x / lpp;
    long pos = (long)blockIdx.x * G + g;
    if (pos >= NPOS) return;
    int ow = (int)(pos % Wout); long t = pos / Wout;
    int oh = (int)(t % Hout);   int n = (int)(t / Hout);
    float4 acc = *(const float4*)(bias + co);
    int sh = stride - 1;                       // stride in {1,2}: mask/shift trick
    for (int kh = 0; kh < KH; ++kh) {
        int ih;
        if (TR) { int q = oh + pad - kh; if (q & sh) continue; ih = q >> sh; }
        else    { ih = oh * stride - pad + kh; }
        if (ih < 0 || ih >= Hin) continue;
        for (int kw = 0; kw < KW; ++kw) {
            int iw;
            if (TR) { int q = ow + pad - kw; if (q & sh) continue; iw = q >> sh; }
            else    { iw = ow * stride - pad + kw; }
            if (iw < 0 || iw >= Win) continue;
            long ib = (long)n * sN + (long)ih * sH + (long)iw * sW;
            const float* wp = wt + (long)(kh * KW + kw) * Cin * Cout + co;
            if (sC == 1 && (Cin & 3) == 0) {   // NHWC fast path
                for (int ci = 0; ci < Cin; ci += 4) {
                    float4 iv = load4(in + ib + ci);
                    const float* w0 = wp + (long)ci * Cout;
                    float4 wa = *(const float4*)(w0);
                    float4 wb = *(const float4*)(w0 + Cout);
                    float4 wc = *(const float4*)(w0 + 2 * Cout);
                    float4 wd = *(const float4*)(w0 + 3 * Cout);
                    acc.x = fmaf(iv.x, wa.x, acc.x); acc.y = fmaf(iv.x, wa.y, acc.y);
                    acc.z = fmaf(iv.x, wa.z, acc.z); acc.w = fmaf(iv.x, wa.w, acc.w);
                    acc.x = fmaf(iv.y, wb.x, acc.x); acc.y = fmaf(iv.y, wb.y, acc.y);
                    acc.z = fmaf(iv.y, wb.z, acc.z); acc.w = fmaf(iv.y, wb.w, acc.w);
                    acc.x = fmaf(iv.z, wc.x, acc.x); acc.y = fmaf(iv.z, wc.y, acc.y);
                    acc.z = fmaf(iv.z, wc.z, acc.z); acc.w = fmaf(iv.z, wc.w, acc.w);
                    acc.x = fmaf(iv.w, wd.x, acc.x); acc.y = fmaf(iv.w, wd.y, acc.y);
                    acc.z = fmaf(iv.w, wd.z, acc.z); acc.w = fmaf(iv.w, wd.w, acc.w);
                }
            } else {                           // scalar-ci path (x: NCHW, Cin=3)
                for (int ci = 0; ci < Cin; ++ci) {
                    float v = loadS(in, ib + (long)ci * sC);
                    float4 wv = *(const float4*)(wp + (long)ci * Cout);
                    acc.x = fmaf(v, wv.x, acc.x); acc.y = fmaf(v, wv.y, acc.y);
                    acc.z = fmaf(v, wv.z, acc.z); acc.w = fmaf(v, wv.w, acc.w);
                }
            }
        }
    }
    if (RELU) {
        acc.x = fmaxf(acc.x, 0.f); acc.y = fmaxf(acc.y, 0.f);
        acc.z = fmaxf(acc.z, 0.f); acc.w = fmaxf(acc.w, 0.f);
    }
    storeOut(out, pos * Cout + co, acc);
}

// --- dec2: convT k3 s1 p1, Cin=64 -> Cout=3, bf16 NHWC in, fp32 NCHW out
__global__ __launch_bounds__(256) void dec2_kernel(
    const bfraw* __restrict__ in, const float* __restrict__ wt,
    const float* __restrict__ bias, float* __restrict__ out) {
    int pos = blockIdx.x * blockDim.x + threadIdx.x;
    if (pos >= 16 * 256 * 256) return;
    int ow = pos & 255; int t = pos >> 8; int oh = t & 255; int n = t >> 8;
    float a0 = bias[0], a1 = bias[1], a2 = bias[2];
    for (int kh = 0; kh < 3; ++kh) {
        int ih = oh + 1 - kh; if (ih < 0 || ih >= 256) continue;
        for (int kw = 0; kw < 3; ++kw) {
            int iw = ow + 1 - kw; if (iw < 0 || iw >= 256) continue;
            const bfraw* ip = in + ((long)(n * 256 + ih) * 256 + iw) * 64;
            const float* wp = wt + (kh * 3 + kw) * 64 * 3;
            for (int ci = 0; ci < 64; ci += 4) {
                ushort4 u = *(const ushort4*)(ip + ci);
                float v0 = bf2f(u.x), v1 = bf2f(u.y), v2 = bf2f(u.z), v3 = bf2f(u.w);
                const float* w0 = wp + ci * 3;
                a0 = fmaf(v0, w0[0], a0); a1 = fmaf(v0, w0[1],  a1); a2 = fmaf(v0, w0[2],  a2);
                a0 = fmaf(v1, w0[3], a0); a1 = fmaf(v1, w0[4],  a1); a2 = fmaf(v1, w0[5],  a2);
                a0 = fmaf(v2, w0[6], a0); a1 = fmaf(v2, w0[7],  a1); a2 = fmaf(v2, w0[8],  a2);
                a0 = fmaf(v3, w0[9], a0); a1 = fmaf(v3, w0[10], a1); a2 = fmaf(v3, w0[11], a2);
            }
        }
    }
    long sp = (long)n * 3 * 65536; long hw = oh * 256 + ow;
    out[sp + hw] = a0; out[sp + 65536 + hw] = a1; out[sp + 131072 + hw] = a2;
}

// --- VQ: per wave 8 positions x all 512 codes (8 codes/lane). argmin_k(||e||^2-2 z.e)
__global__ __launch_bounds__(256) void vq_kernel(
    const float* __restrict__ ze, const float* __restrict__ emb,
    const float* __restrict__ embT, const float* __restrict__ esq,
    float* __restrict__ zq, int* __restrict__ hist) {
    __shared__ int sIdx[32];
    int tid = threadIdx.x, lane = tid & 63, wv = tid >> 6;
    int posBase = blockIdx.x * 32 + wv * 8;
    float acc[8][8];
#pragma unroll
    for (int p = 0; p < 8; ++p)
#pragma unroll
        for (int j = 0; j < 8; ++j) acc[p][j] = 0.f;
    const float* zp = ze + (long)posBase * 256;
    for (int d = 0; d < 256; ++d) {
        float zs[8];
#pragma unroll
        for (int p = 0; p < 8; ++p) zs[p] = zp[p * 256 + d];   // wave-uniform (L1 hot)
        const float* ep = embT + d * 512 + lane;               // coalesced
#pragma unroll
        for (int j = 0; j < 8; ++j) {
            float ev = ep[j * 64];
#pragma unroll
            for (int p = 0; p < 8; ++p) acc[p][j] = fmaf(ev, zs[p], acc[p][j]);
        }
    }
#pragma unroll
    for (int p = 0; p < 8; ++p) {
        float best = 1e30f; int bk = 0;
#pragma unroll
        for (int j = 0; j < 8; ++j) {
            int k = j * 64 + lane;
            float dist = esq[k] - 2.f * acc[p][j];
            if (dist < best) { best = dist; bk = k; }          // first-min within lane
        }
        for (int off = 32; off; off >>= 1) {                   // wave argmin, k tie-break
            float ov = __shfl_down(best, off, 64);
            int   ok = __shfl_down(bk,   off, 64);
            if (ov < best || (ov == best && ok < bk)) { best = ov; bk = ok; }
        }
        if (lane == 0) { sIdx[wv * 8 + p] = bk; atomicAdd(&hist[bk], 1); }
    }
    __syncthreads();
    int blockPos = blockIdx.x * 32;
    const float4* emb4 = (const float4*)emb;
    float4* zq4 = (float4*)(zq + (long)blockPos * 256);
    for (int i = tid; i < 32 * 64; i += 256) {                 // z_q gather, coalesced
        int p = i >> 6, c = i & 63;
        zq4[i] = emb4[sIdx[p] * 64 + c];
    }
}

// --- perplexity from histogram
__global__ void ppl_kernel(const int* __restrict__ hist, float* __restrict__ outp) {
    __shared__ float red[512];
    int t = threadIdx.x;
    float p = (float)hist[t] * (1.0f / 65536.0f);
    red[t] = p * logf(p + 1e-10f);
    __syncthreads();
    for (int s = 256; s; s >>= 1) { if (t < s) red[t] += red[t + s]; __syncthreads(); }
    if (t == 0) *outp = expf(-red[0]);
}

extern "C" void kernel_launch(void* const* d_in, const int* in_sizes, int n_in,
                              void* d_out, int out_size, void* d_ws, size_t ws_size,
                              hipStream_t stream) {
    const float* x       = (const float*)d_in[0];
    const float* w_enc1  = (const float*)d_in[1];
    const float* b_enc1  = (const float*)d_in[2];
    const float* w_enc2  = (const float*)d_in[3];
    const float* b_enc2  = (const float*)d_in[4];
    const float* w_prevq = (const float*)d_in[5];
    const float* b_prevq = (const float*)d_in[6];
    const float* emb     = (const float*)d_in[7];
    const float* w_post  = (const float*)d_in[8];
    const float* b_post  = (const float*)d_in[9];
    const float* w_dec1  = (const float*)d_in[10];
    const float* b_dec1  = (const float*)d_in[11];
    const float* w_dec2  = (const float*)d_in[12];
    const float* b_dec2  = (const float*)d_in[13];

    float* out = (float*)d_out;
    float* xr  = out;                     // 3,145,728
    float* ze  = out + 3145728;           // 16,777,216
    float* zq  = ze + 16777216;           // 16,777,216
    float* ppl = zq + 16777216;           // 1

    // workspace carve (float units for small region, bytes for bf16 buffers)
    float* w1t  = (float*)d_ws;           // 3072   (pad 4096)
    float* w2t  = w1t + 4096;             // 131072
    float* w3t  = w2t + 131072;           // 294912
    float* wpt  = w3t + 294912;           // 524288
    float* wd1t = wpt + 524288;           // 131072
    float* wd2t = wd1t + 131072;          // 1728   (pad 2048)
    float* esq  = wd2t + 2048;            // 512
    float* embT = esq + 512;              // 131072
    int*   hist = (int*)(embT + 131072);  // 512
    char*  wsb   = (char*)d_ws;
    bfraw* h2    = (bfraw*)(wsb + 4878336);   // 8,388,608 elems
    bfraw* dpost = (bfraw*)(wsb + 21655552);  // 33,554,432 elems
    bfraw* ddec1 = (bfraw*)(wsb + 88764416);  // 67,108,864 elems -> end ~213 MB
    bfraw* h1    = (bfraw*)ze;            // alias: h1 dies before prevq writes z_e

    // weight transforms + emb precomputes
    wt_kernel<<<16, 256, 0, stream>>>(w_enc1, w1t, 64, 3, 4, 4, 0);
    wt_kernel<<<512, 256, 0, stream>>>(w_enc2, w2t, 128, 64, 4, 4, 0);
    wt_kernel<<<1152, 256, 0, stream>>>(w_prevq, w3t, 256, 128, 3, 3, 0);
    wt_kernel<<<2048, 256, 0, stream>>>(w_post, wpt, 128, 256, 4, 4, 1);
    wt_kernel<<<512, 256, 0, stream>>>(w_dec1, wd1t, 64, 128, 4, 4, 1);
    wt_kernel<<<8, 256, 0, stream>>>(w_dec2, wd2t, 3, 64, 3, 3, 1);
    embsq_kernel<<<512, 64, 0, stream>>>(emb, esq);
    embT_kernel<<<512, 256, 0, stream>>>(emb, embT);
    hipMemsetAsync(hist, 0, 512 * sizeof(int), stream);

    // encoder
    conv_kernel<float, bfraw, true, false><<<16384, 256, 0, stream>>>(
        x, w1t, b_enc1, h1, 262144, 256, 256, 3, 128, 128, 64, 4, 4, 2, 1,
        196608L, 256L, 1L, 65536L);                                   // x is NCHW
    conv_kernel<bfraw, bfraw, true, false><<<8192, 256, 0, stream>>>(
        h1, w2t, b_enc2, h2, 65536, 128, 128, 64, 64, 64, 128, 4, 4, 2, 1,
        1048576L, 8192L, 64L, 1L);
    conv_kernel<bfraw, float, false, false><<<16384, 256, 0, stream>>>(
        h2, w3t, b_prevq, ze, 65536, 64, 64, 128, 64, 64, 256, 3, 3, 1, 1,
        524288L, 8192L, 128L, 1L);                                    // writes z_e

    // VQ
    vq_kernel<<<2048, 256, 0, stream>>>(ze, emb, embT, esq, zq, hist);
    ppl_kernel<<<1, 512, 0, stream>>>(hist, ppl);

    // decoder (dec_in == z_q numerically; read straight from d_out)
    conv_kernel<float, bfraw, false, true><<<32768, 256, 0, stream>>>(
        zq, wpt, b_post, dpost, 262144, 64, 64, 256, 128, 128, 128, 4, 4, 2, 1,
        1048576L, 16384L, 256L, 1L);
    conv_kernel<bfraw, bfraw, true, true><<<65536, 256, 0, stream>>>(
        dpost, wd1t, b_dec1, ddec1, 1048576, 128, 128, 128, 256, 256, 64, 4, 4, 2, 1,
        2097152L, 16384L, 128L, 1L);
    dec2_kernel<<<4096, 256, 0, stream>>>(ddec1, wd2t, b_dec2, xr);
}

// Round 2
// 1767.684 us; speedup vs baseline: 13.0638x; 13.0638x over previous
//
#include <hip/hip_runtime.h>
#include <stdint.h>

// ---------------------------------------------------------------------------
// VQ-VAE forward on MI355X. Round 1: bf16 MFMA implicit-GEMM for the four
// big convs (enc2/prevq/post/dec1); convT via 4 parity classes (each an
// exact 4-tap stride-1 conv). global_load_lds(16B) staging, 16x16x32 bf16
// MFMA, 64x64 macro-tile/wave. enc1/dec2/VQ kept direct from round 0.
// ---------------------------------------------------------------------------

typedef unsigned short bfraw;
typedef __attribute__((ext_vector_type(8))) short s16x8;
typedef __attribute__((ext_vector_type(4))) float f32x4;

__device__ __forceinline__ float bf2f(bfraw u) {
    union { unsigned int i; float f; } v; v.i = ((unsigned int)u) << 16; return v.f;
}
__device__ __forceinline__ bfraw f2bf(float f) {
    union { float f; unsigned int i; } v; v.f = f;
    unsigned int r = v.i + 0x7FFFu + ((v.i >> 16) & 1u);   // RNE
    return (bfraw)(r >> 16);
}

__device__ __forceinline__ float4 load4(const float* p) { return *(const float4*)p; }
__device__ __forceinline__ float4 load4(const bfraw* p) {
    ushort4 u = *(const ushort4*)p;
    float4 r; r.x = bf2f(u.x); r.y = bf2f(u.y); r.z = bf2f(u.z); r.w = bf2f(u.w); return r;
}
__device__ __forceinline__ float loadS(const float* p, long i) { return p[i]; }
__device__ __forceinline__ float loadS(const bfraw* p, long i) { return bf2f(p[i]); }
__device__ __forceinline__ void storeOut(float* o, long i, float4 v) { *(float4*)(o + i) = v; }
__device__ __forceinline__ void storeOut(bfraw* o, long i, float4 v) {
    ushort4 u; u.x = f2bf(v.x); u.y = f2bf(v.y); u.z = f2bf(v.z); u.w = f2bf(v.w);
    *(ushort4*)(o + i) = u;
}

// async 16B global->LDS (CK-style addrspace casts). LDS dest: wave-uniform
// base + lane*16.
__device__ __forceinline__ void gl_lds16(const void* g, void* l) {
    auto gp = reinterpret_cast<const __attribute__((address_space(1))) unsigned int*>(
        reinterpret_cast<uintptr_t>(g));
    auto lp = reinterpret_cast<__attribute__((address_space(3))) unsigned int*>(
        reinterpret_cast<uintptr_t>(l));
    __builtin_amdgcn_global_load_lds(gp, lp, 16, 0, 0);
}

// --- weight transform (fp32, [tap][ci][co]) for direct convs (enc1, dec2)
__global__ void wt_kernel(const float* __restrict__ w, float* __restrict__ wt,
                          int Cout, int Cin, int KH, int KW, int transposed) {
    int n = Cout * Cin * KH * KW;
    for (int i = blockIdx.x * blockDim.x + threadIdx.x; i < n; i += gridDim.x * blockDim.x) {
        int co = i % Cout; int t = i / Cout;
        int ci = t % Cin;  int tap = t / Cin;
        int kw = tap % KW; int kh = tap / KW;
        float v = transposed ? w[(((long)ci * Cout + co) * KH + kh) * KW + kw]
                             : w[(((long)co * Cin + ci) * KH + kh) * KW + kw];
        wt[i] = v;
    }
}

// --- weight transform (bf16, [co][tap][ci]) for MFMA convs (B as [n][k])
__global__ void wtb_kernel(const float* __restrict__ w, bfraw* __restrict__ wt,
                           int Cout, int Cin, int KH, int KW, int transposed) {
    int n = Cout * Cin * KH * KW;
    int NT = KH * KW;
    for (int i = blockIdx.x * blockDim.x + threadIdx.x; i < n; i += gridDim.x * blockDim.x) {
        int ci = i % Cin; int t = i / Cin;
        int tap = t % NT; int co = t / NT;
        int kh = tap / KW, kw = tap % KW;
        float v = transposed ? w[(((long)ci * Cout + co) * KH + kh) * KW + kw]
                             : w[(((long)co * Cin + ci) * KH + kh) * KW + kw];
        wt[i] = f2bf(v);
    }
}

// --- emb row norms
__global__ void embsq_kernel(const float* __restrict__ emb, float* __restrict__ esq) {
    int k = blockIdx.x, lane = threadIdx.x;
    float s = 0.f;
    for (int d = lane; d < 256; d += 64) { float v = emb[k * 256 + d]; s += v * v; }
    for (int o = 32; o; o >>= 1) s += __shfl_down(s, o, 64);
    if (lane == 0) esq[k] = s;
}

// --- emb transpose
__global__ void embT_kernel(const float* __restrict__ emb, float* __restrict__ embT) {
    int i = blockIdx.x * blockDim.x + threadIdx.x;
    if (i < 512 * 256) { int k = i >> 8; int d = i & 255; embT[d * 512 + k] = emb[i]; }
}

// --- direct conv (kept for enc1 only: Cin=3, K=48, tiny)
template <typename TIN, typename TOUT, bool RELU, bool TR>
__global__ __launch_bounds__(256) void conv_kernel(
    const TIN* __restrict__ in, const float* __restrict__ wt,
    const float* __restrict__ bias, TOUT* __restrict__ out,
    int NPOS, int Hin, int Win, int Cin, int Hout, int Wout, int Cout,
    int KH, int KW, int stride, int pad,
    long sN, long sH, long sW, long sC) {
    int lpp = Cout >> 2;
    int g   = threadIdx.x / lpp;
    int co  = (threadIdx.x % lpp) << 2;
    int G   = blockDim.x / lpp;
    long pos = (long)blockIdx.x * G + g;
    if (pos >= NPOS) return;
    int ow = (int)(pos % Wout); long t = pos / Wout;
    int oh = (int)(t % Hout);   int n = (int)(t / Hout);
    float4 acc = *(const float4*)(bias + co);
    int sh = stride - 1;
    for (int kh = 0; kh < KH; ++kh) {
        int ih;
        if (TR) { int q = oh + pad - kh; if (q & sh) continue; ih = q >> sh; }
        else    { ih = oh * stride - pad + kh; }
        if (ih < 0 || ih >= Hin) continue;
        for (int kw = 0; kw < KW; ++kw) {
            int iw;
            if (TR) { int q = ow + pad - kw; if (q & sh) continue; iw = q >> sh; }
            else    { iw = ow * stride - pad + kw; }
            if (iw < 0 || iw >= Win) continue;
            long ib = (long)n * sN + (long)ih * sH + (long)iw * sW;
            const float* wp = wt + (long)(kh * KW + kw) * Cin * Cout + co;
            for (int ci = 0; ci < Cin; ++ci) {
                float v = loadS(in, ib + (long)ci * sC);
                float4 wv = *(const float4*)(wp + (long)ci * Cout);
                acc.x = fmaf(v, wv.x, acc.x); acc.y = fmaf(v, wv.y, acc.y);
                acc.z = fmaf(v, wv.z, acc.z); acc.w = fmaf(v, wv.w, acc.w);
            }
        }
    }
    if (RELU) {
        acc.x = fmaxf(acc.x, 0.f); acc.y = fmaxf(acc.y, 0.f);
        acc.z = fmaxf(acc.z, 0.f); acc.w = fmaxf(acc.w, 0.f);
    }
    storeOut(out, pos * Cout + co, acc);
}

// ---------------------------------------------------------------------------
// MFMA implicit GEMM: C[M x N] = A[M x K] * B[K x N]; A rows = output
// positions (gathered conv patches), B = weights [co][tap][ci] (as [n][k]).
// Block = 256 thr (4 waves, WM x WN grid of 64x64 wave macro-tiles).
// K-slice of 32 always lies within one tap (Cin % 32 == 0).
// TR: output positions are a parity-class subgrid (oh=2*oh2+py, ow=2*ow2+px);
//     tap table packed 16b/entry in `pack`: (dy+1)<<8 | (dx+1)<<4 | wtap.
// ---------------------------------------------------------------------------
template<int BM, int BN, int WM, int WN, bool TR, bool RELU, bool OUTF32>
__global__ __launch_bounds__(256) void igemm_kernel(
    const bfraw* __restrict__ in, const bfraw* __restrict__ wt,
    const float* __restrict__ bias, void* __restrict__ outv,
    const bfraw* __restrict__ zp,
    int Hin, int Win, int Cin, int sf, int NTW, int Ksteps,
    int lw, int lh, int N, int KW, int pad, int py, int px,
    unsigned long long pack)
{
    constexpr int APASS = BM / 64, BPASS = BN / 64;
    __shared__ __align__(16) bfraw ldsA[BM * 32];
    __shared__ __align__(16) bfraw ldsB[BN * 32];
    const int tid = threadIdx.x, lane = tid & 63, wv = tid >> 6;
    const int wm = wv / WN, wn = wv % WN;
    const int lrow = lane >> 2, lkof = (lane & 3) * 8;   // 16B per lane
    const int blockM = blockIdx.x, n0 = blockIdx.y * BN;
    const int Wm1 = (1 << lw) - 1, Hm1 = (1 << lh) - 1;

    long baseA[APASS]; int ihb[APASS], iwb[APASS];
#pragma unroll
    for (int p = 0; p < APASS; ++p) {
        int m = p * 64 + wv * 16 + lrow;
        int pos = blockM * BM + m;
        int ow = pos & Wm1; int t = pos >> lw;
        int oh = t & Hm1;   int nb = t >> lh;
        ihb[p] = oh * sf; iwb[p] = ow * sf;
        baseA[p] = ((long)(nb * Hin + ihb[p]) * Win + iwb[p]) * (long)Cin + lkof;
    }
    long baseB[BPASS];
#pragma unroll
    for (int p = 0; p < BPASS; ++p) {
        int nl = p * 64 + wv * 16 + lrow;
        baseB[p] = (long)(n0 + nl) * ((long)NTW * Cin) + lkof;
    }

    f32x4 acc[4][4];
#pragma unroll
    for (int i = 0; i < 4; ++i)
#pragma unroll
        for (int j = 0; j < 4; ++j) acc[i][j] = (f32x4)0.f;

    int ci0 = 0, tslot = 0, dy, dx, wk;
    if (TR) {
        unsigned e = (unsigned)pack & 0xFFFFu;
        dy = (int)((e >> 8) & 3) - 1; dx = (int)((e >> 4) & 3) - 1; wk = (int)(e & 15u);
    } else { dy = -pad; dx = -pad; wk = 0; }

    const int quad = lane >> 4, r16 = lane & 15;

    for (int ks = 0; ks < Ksteps; ++ks) {
        long offA = ((long)(dy * Win + dx)) * Cin + ci0;
        long offB = (long)wk * Cin + ci0;
#pragma unroll
        for (int p = 0; p < APASS; ++p) {
            int ih = ihb[p] + dy, iw = iwb[p] + dx;
            bool ok = ((unsigned)ih < (unsigned)Hin) & ((unsigned)iw < (unsigned)Win);
            const bfraw* g = ok ? (in + baseA[p] + offA) : (zp + lkof);
            gl_lds16(g, &ldsA[(p * 64 + wv * 16) * 32]);
        }
#pragma unroll
        for (int p = 0; p < BPASS; ++p)
            gl_lds16(wt + baseB[p] + offB, &ldsB[(p * 64 + wv * 16) * 32]);
        __syncthreads();
        s16x8 af[4], bf[4];
#pragma unroll
        for (int i = 0; i < 4; ++i)
            af[i] = *(const s16x8*)&ldsA[(wm * 64 + i * 16 + r16) * 32 + quad * 8];
#pragma unroll
        for (int j = 0; j < 4; ++j)
            bf[j] = *(const s16x8*)&ldsB[(wn * 64 + j * 16 + r16) * 32 + quad * 8];
#pragma unroll
        for (int i = 0; i < 4; ++i)
#pragma unroll
            for (int j = 0; j < 4; ++j)
                acc[i][j] = __builtin_amdgcn_mfma_f32_16x16x32_bf16(af[i], bf[j], acc[i][j], 0, 0, 0);
        __syncthreads();
        ci0 += 32;
        if (ci0 == Cin) {
            ci0 = 0; ++tslot;
            if (TR) {
                unsigned e = (unsigned)(pack >> (tslot * 16)) & 0xFFFFu;
                dy = (int)((e >> 8) & 3) - 1; dx = (int)((e >> 4) & 3) - 1; wk = (int)(e & 15u);
            } else { ++wk; ++dx; if (dx == KW - pad) { dx = -pad; ++dy; } }
        }
    }

    // epilogue: D[row][col], row = m-tile*16 + quad*4 + reg, col = lane&15
#pragma unroll
    for (int j = 0; j < 4; ++j) {
        int col = wn * 64 + j * 16 + r16; int ng = n0 + col;
        float bv = bias[ng];
#pragma unroll
        for (int i = 0; i < 4; ++i) {
            int mb = wm * 64 + i * 16 + quad * 4;
#pragma unroll
            for (int r = 0; r < 4; ++r) {
                int pos2 = blockM * BM + mb + r;
                long oaddr;
                if (TR) {
                    int ow2 = pos2 & Wm1; int t = pos2 >> lw;
                    int oh2 = t & Hm1;    int nb = t >> lh;
                    int oh = 2 * oh2 + py, ow = 2 * ow2 + px;
                    oaddr = ((long)(((nb << (lh + 1)) + oh) << (lw + 1)) + ow) * N + ng;
                } else {
                    oaddr = (long)pos2 * N + ng;
                }
                float v = acc[i][j][r] + bv;
                if (RELU) v = fmaxf(v, 0.f);
                if (OUTF32) ((float*)outv)[oaddr] = v;
                else        ((bfraw*)outv)[oaddr] = f2bf(v);
            }
        }
    }
}

// --- dec2: convT k3 s1 p1, Cin=64 -> Cout=3, bf16 NHWC in, fp32 NCHW out
__global__ __launch_bounds__(256) void dec2_kernel(
    const bfraw* __restrict__ in, const float* __restrict__ wt,
    const float* __restrict__ bias, float* __restrict__ out) {
    int pos = blockIdx.x * blockDim.x + threadIdx.x;
    if (pos >= 16 * 256 * 256) return;
    int ow = pos & 255; int t = pos >> 8; int oh = t & 255; int n = t >> 8;
    float a0 = bias[0], a1 = bias[1], a2 = bias[2];
    for (int kh = 0; kh < 3; ++kh) {
        int ih = oh + 1 - kh; if (ih < 0 || ih >= 256) continue;
        for (int kw = 0; kw < 3; ++kw) {
            int iw = ow + 1 - kw; if (iw < 0 || iw >= 256) continue;
            const bfraw* ip = in + ((long)(n * 256 + ih) * 256 + iw) * 64;
            const float* wp = wt + (kh * 3 + kw) * 64 * 3;
            for (int ci = 0; ci < 64; ci += 4) {
                ushort4 u = *(const ushort4*)(ip + ci);
                float v0 = bf2f(u.x), v1 = bf2f(u.y), v2 = bf2f(u.z), v3 = bf2f(u.w);
                const float* w0 = wp + ci * 3;
                a0 = fmaf(v0, w0[0], a0); a1 = fmaf(v0, w0[1],  a1); a2 = fmaf(v0, w0[2],  a2);
                a0 = fmaf(v1, w0[3], a0); a1 = fmaf(v1, w0[4],  a1); a2 = fmaf(v1, w0[5],  a2);
                a0 = fmaf(v2, w0[6], a0); a1 = fmaf(v2, w0[7],  a1); a2 = fmaf(v2, w0[8],  a2);
                a0 = fmaf(v3, w0[9], a0); a1 = fmaf(v3, w0[10], a1); a2 = fmaf(v3, w0[11], a2);
            }
        }
    }
    long sp = (long)n * 3 * 65536; long hw = oh * 256 + ow;
    out[sp + hw] = a0; out[sp + 65536 + hw] = a1; out[sp + 131072 + hw] = a2;
}

// --- VQ: argmin_k(||e||^2 - 2 z.e); emits fp32 z_q (d_out) + bf16 z_q (ws)
__global__ __launch_bounds__(256) void vq_kernel(
    const float* __restrict__ ze, const float* __restrict__ emb,
    const float* __restrict__ embT, const float* __restrict__ esq,
    float* __restrict__ zq, bfraw* __restrict__ zqb, int* __restrict__ hist) {
    __shared__ int sIdx[32];
    int tid = threadIdx.x, lane = tid & 63, wv = tid >> 6;
    int posBase = blockIdx.x * 32 + wv * 8;
    float acc[8][8];
#pragma unroll
    for (int p = 0; p < 8; ++p)
#pragma unroll
        for (int j = 0; j < 8; ++j) acc[p][j] = 0.f;
    const float* zp = ze + (long)posBase * 256;
    for (int d = 0; d < 256; ++d) {
        float zs[8];
#pragma unroll
        for (int p = 0; p < 8; ++p) zs[p] = zp[p * 256 + d];
        const float* ep = embT + d * 512 + lane;
#pragma unroll
        for (int j = 0; j < 8; ++j) {
            float ev = ep[j * 64];
#pragma unroll
            for (int p = 0; p < 8; ++p) acc[p][j] = fmaf(ev, zs[p], acc[p][j]);
        }
    }
#pragma unroll
    for (int p = 0; p < 8; ++p) {
        float best = 1e30f; int bk = 0;
#pragma unroll
        for (int j = 0; j < 8; ++j) {
            int k = j * 64 + lane;
            float dist = esq[k] - 2.f * acc[p][j];
            if (dist < best) { best = dist; bk = k; }
        }
        for (int off = 32; off; off >>= 1) {
            float ov = __shfl_down(best, off, 64);
            int   ok = __shfl_down(bk,   off, 64);
            if (ov < best || (ov == best && ok < bk)) { best = ov; bk = ok; }
        }
        if (lane == 0) { sIdx[wv * 8 + p] = bk; atomicAdd(&hist[bk], 1); }
    }
    __syncthreads();
    long blockPos = (long)blockIdx.x * 32;
    const float4* emb4 = (const float4*)emb;
    float4*  zq4  = (float4*)(zq + blockPos * 256);
    ushort4* zqb4 = (ushort4*)(zqb + blockPos * 256);
    for (int i = tid; i < 32 * 64; i += 256) {
        int p = i >> 6, c = i & 63;
        float4 v = emb4[sIdx[p] * 64 + c];
        zq4[i] = v;
        ushort4 u; u.x = f2bf(v.x); u.y = f2bf(v.y); u.z = f2bf(v.z); u.w = f2bf(v.w);
        zqb4[i] = u;
    }
}

// --- perplexity
__global__ void ppl_kernel(const int* __restrict__ hist, float* __restrict__ outp) {
    __shared__ float red[512];
    int t = threadIdx.x;
    float p = (float)hist[t] * (1.0f / 65536.0f);
    red[t] = p * logf(p + 1e-10f);
    __syncthreads();
    for (int s = 256; s; s >>= 1) { if (t < s) red[t] += red[t + s]; __syncthreads(); }
    if (t == 0) *outp = expf(-red[0]);
}

// host: pack convT parity-class tap table (4 entries x 16 bits)
static unsigned long long packFor(int py, int px) {
    unsigned long long pk = 0; int s = 0;
    for (int kh = 0; kh < 4; ++kh) {
        if (((py + 1 - kh) & 1) != 0) continue;
        int dy = (py + 1 - kh) / 2;
        for (int kw = 0; kw < 4; ++kw) {
            if (((px + 1 - kw) & 1) != 0) continue;
            int dx = (px + 1 - kw) / 2;
            unsigned e = ((unsigned)(dy + 1) << 8) | ((unsigned)(dx + 1) << 4) | (unsigned)(kh * 4 + kw);
            pk |= (unsigned long long)e << (16 * s); ++s;
        }
    }
    return pk;
}

extern "C" void kernel_launch(void* const* d_in, const int* in_sizes, int n_in,
                              void* d_out, int out_size, void* d_ws, size_t ws_size,
                              hipStream_t stream) {
    const float* x       = (const float*)d_in[0];
    const float* w_enc1  = (const float*)d_in[1];
    const float* b_enc1  = (const float*)d_in[2];
    const float* w_enc2  = (const float*)d_in[3];
    const float* b_enc2  = (const float*)d_in[4];
    const float* w_prevq = (const float*)d_in[5];
    const float* b_prevq = (const float*)d_in[6];
    const float* emb     = (const float*)d_in[7];
    const float* w_post  = (const float*)d_in[8];
    const float* b_post  = (const float*)d_in[9];
    const float* w_dec1  = (const float*)d_in[10];
    const float* b_dec1  = (const float*)d_in[11];
    const float* w_dec2  = (const float*)d_in[12];
    const float* b_dec2  = (const float*)d_in[13];

    float* out = (float*)d_out;
    float* xr  = out;                     // 3,145,728
    float* ze  = out + 3145728;           // 16,777,216
    float* zq  = ze + 16777216;           // 16,777,216
    float* ppl = zq + 16777216;           // 1

    // ---- workspace carve (bytes) ----
    char* W = (char*)d_ws;
    float* w1t  = (float*)(W + 0);          // enc1 fp32 [tap][ci][co]   12 KB
    float* wd2t = (float*)(W + 16384);      // dec2 fp32                  7 KB
    float* esq  = (float*)(W + 24576);      // 2 KB
    float* embT = (float*)(W + 32768);      // 512 KB -> 557056
    int*   hist = (int*)(W + 557056);       // 2 KB
    bfraw* zp   = (bfraw*)(W + 559360);     // zero page, 256 B
    bfraw* w2b  = (bfraw*)(W + 560128);     // enc2  bf16 [co][16][64]   256 KB
    bfraw* w3b  = (bfraw*)(W + 822272);     // prevq bf16 [co][9][128]   576 KB
    bfraw* wpb  = (bfraw*)(W + 1412096);    // post  bf16 [co][16][256]  1 MB
    bfraw* wd1b = (bfraw*)(W + 2460672);    // dec1  bf16 [co][16][128]  256 KB
    // bufX (134.2 MB): h2 -> zqb -> ddec1 (sequential lifetimes)
    bfraw* bufX = (bfraw*)(W + 4194304);
    bfraw* h2    = bufX;                    // 8.4M elems (enc2 out)
    bfraw* zqb   = bufX;                    // 16.8M elems (z_q bf16)
    bfraw* ddec1 = bufX;                    // 67.1M elems (dec1 out)
    // bufY (67.1 MB): dpost
    bfraw* dpost = (bfraw*)(W + 138412032);
    bfraw* h1    = (bfraw*)ze;              // alias: h1 dies before prevq writes z_e

    // ---- weight transforms + precomputes ----
    wt_kernel<<<16, 256, 0, stream>>>(w_enc1, w1t, 64, 3, 4, 4, 0);
    wt_kernel<<<8, 256, 0, stream>>>(w_dec2, wd2t, 3, 64, 3, 3, 1);
    wtb_kernel<<<512, 256, 0, stream>>>(w_enc2, w2b, 128, 64, 4, 4, 0);
    wtb_kernel<<<1152, 256, 0, stream>>>(w_prevq, w3b, 256, 128, 3, 3, 0);
    wtb_kernel<<<2048, 256, 0, stream>>>(w_post, wpb, 128, 256, 4, 4, 1);
    wtb_kernel<<<512, 256, 0, stream>>>(w_dec1, wd1b, 64, 128, 4, 4, 1);
    embsq_kernel<<<512, 64, 0, stream>>>(emb, esq);
    embT_kernel<<<512, 256, 0, stream>>>(emb, embT);
    hipMemsetAsync(hist, 0, 512 * sizeof(int), stream);
    hipMemsetAsync(zp, 0, 256, stream);

    // ---- encoder ----
    conv_kernel<float, bfraw, true, false><<<16384, 256, 0, stream>>>(
        x, w1t, b_enc1, h1, 262144, 256, 256, 3, 128, 128, 64, 4, 4, 2, 1,
        196608L, 256L, 1L, 65536L);                      // x NCHW -> h1 NHWC bf16
    // enc2: M=65536,K=16*64,N=128
    igemm_kernel<128, 128, 2, 2, false, true, false><<<dim3(512, 1), 256, 0, stream>>>(
        h1, w2b, b_enc2, h2, zp, 128, 128, 64, 2, 16, 32, 6, 6, 128, 4, 1, 0, 0, 0ULL);
    // prevq: M=65536,K=9*128,N=256 -> ze fp32
    igemm_kernel<128, 128, 2, 2, false, false, true><<<dim3(512, 2), 256, 0, stream>>>(
        h2, w3b, b_prevq, ze, zp, 64, 64, 128, 1, 9, 36, 6, 6, 256, 3, 1, 0, 0, 0ULL);

    // ---- VQ ----
    vq_kernel<<<2048, 256, 0, stream>>>(ze, emb, embT, esq, zq, zqb, hist);
    ppl_kernel<<<1, 512, 0, stream>>>(hist, ppl);

    // ---- decoder ----
    // post: convT k4 s2 p1, 4 parity classes, each M=65536,K=4*256,N=128
    for (int cls = 0; cls < 4; ++cls) {
        int py = cls >> 1, px = cls & 1;
        igemm_kernel<128, 128, 2, 2, true, false, false><<<dim3(512, 1), 256, 0, stream>>>(
            zqb, wpb, b_post, dpost, zp, 64, 64, 256, 1, 16, 32, 6, 6, 128, 4, 1,
            py, px, packFor(py, px));
    }
    // dec1: convT k4 s2 p1 + relu, 4 classes, each M=262144,K=4*128,N=64
    for (int cls = 0; cls < 4; ++cls) {
        int py = cls >> 1, px = cls & 1;
        igemm_kernel<256, 64, 4, 1, true, true, false><<<dim3(1024, 1), 256, 0, stream>>>(
            dpost, wd1b, b_dec1, ddec1, zp, 128, 128, 128, 1, 16, 16, 7, 7, 64, 4, 1,
            py, px, packFor(py, px));
    }
    dec2_kernel<<<4096, 256, 0, stream>>>(ddec1, wd2t, b_dec2, xr);
}

// Round 3
// 1248.126 us; speedup vs baseline: 18.5018x; 1.4163x over previous
//
#include <hip/hip_runtime.h>
#include <stdint.h>

// ---------------------------------------------------------------------------
// VQ-VAE forward on MI355X. Round 2:
//  - dec2: 2D-tiled (16x16) direct conv — kills the 14x HBM/L3 over-fetch
//    the 1x256-strip version had (2.08 GB -> ~0.2 GB predicted).
//  - enc1: im2col (xpack) + bf16 MFMA igemm (K=48 padded to 64).
//  - enc2/prevq/post/dec1: bf16 MFMA implicit-GEMM (unchanged from R1).
// ---------------------------------------------------------------------------

typedef unsigned short bfraw;
typedef __attribute__((ext_vector_type(8))) short s16x8;
typedef __attribute__((ext_vector_type(4))) float f32x4;

__device__ __forceinline__ float bf2f(bfraw u) {
    union { unsigned int i; float f; } v; v.i = ((unsigned int)u) << 16; return v.f;
}
__device__ __forceinline__ float bflo(unsigned int u) {
    union { unsigned int i; float f; } v; v.i = u << 16; return v.f;
}
__device__ __forceinline__ float bfhi(unsigned int u) {
    union { unsigned int i; float f; } v; v.i = u & 0xFFFF0000u; return v.f;
}
__device__ __forceinline__ bfraw f2bf(float f) {
    union { float f; unsigned int i; } v; v.f = f;
    unsigned int r = v.i + 0x7FFFu + ((v.i >> 16) & 1u);   // RNE
    return (bfraw)(r >> 16);
}

// async 16B global->LDS. LDS dest: wave-uniform base + lane*16.
__device__ __forceinline__ void gl_lds16(const void* g, void* l) {
    auto gp = reinterpret_cast<const __attribute__((address_space(1))) unsigned int*>(
        reinterpret_cast<uintptr_t>(g));
    auto lp = reinterpret_cast<__attribute__((address_space(3))) unsigned int*>(
        reinterpret_cast<uintptr_t>(l));
    __builtin_amdgcn_global_load_lds(gp, lp, 16, 0, 0);
}

// --- weight transform (fp32, [tap][ci][co]) for dec2
__global__ void wt_kernel(const float* __restrict__ w, float* __restrict__ wt,
                          int Cout, int Cin, int KH, int KW, int transposed) {
    int n = Cout * Cin * KH * KW;
    for (int i = blockIdx.x * blockDim.x + threadIdx.x; i < n; i += gridDim.x * blockDim.x) {
        int co = i % Cout; int t = i / Cout;
        int ci = t % Cin;  int tap = t / Cin;
        int kw = tap % KW; int kh = tap / KW;
        float v = transposed ? w[(((long)ci * Cout + co) * KH + kh) * KW + kw]
                             : w[(((long)co * Cin + ci) * KH + kh) * KW + kw];
        wt[i] = v;
    }
}

// --- weight transform (bf16, [co][tap][ci]) for MFMA convs (B as [n][k])
__global__ void wtb_kernel(const float* __restrict__ w, bfraw* __restrict__ wt,
                           int Cout, int Cin, int KH, int KW, int transposed) {
    int n = Cout * Cin * KH * KW;
    int NT = KH * KW;
    for (int i = blockIdx.x * blockDim.x + threadIdx.x; i < n; i += gridDim.x * blockDim.x) {
        int ci = i % Cin; int t = i / Cin;
        int tap = t % NT; int co = t / NT;
        int kh = tap / KW, kw = tap % KW;
        float v = transposed ? w[(((long)ci * Cout + co) * KH + kh) * KW + kw]
                             : w[(((long)co * Cin + ci) * KH + kh) * KW + kw];
        wt[i] = f2bf(v);
    }
}

// --- enc1 weight pack: wb1[co][k64], k=(kh*4+kw)*3+ci (48 real, 16 zero)
__global__ void wb1_kernel(const float* __restrict__ w, bfraw* __restrict__ wt) {
    int i = blockIdx.x * 256 + threadIdx.x;
    if (i >= 4096) return;
    int k = i & 63, co = i >> 6;
    bfraw v = 0;
    if (k < 48) {
        int ci = k % 3, tap = k / 3, kh = tap >> 2, kw = tap & 3;
        v = f2bf(w[(((long)co * 3 + ci) * 4 + kh) * 4 + kw]);
    }
    wt[(long)co * 64 + k] = v;
}

// --- enc1 im2col: x NCHW fp32 -> A0[pos][64] bf16 (48 patch vals + 16 zeros)
__global__ __launch_bounds__(256) void xpack_kernel(const float* __restrict__ x,
                                                    bfraw* __restrict__ a0) {
    int pos = blockIdx.x * 256 + threadIdx.x;        // 262144
    int ow = pos & 127, oh = (pos >> 7) & 127, n = pos >> 14;
    __align__(16) bfraw v[64];
#pragma unroll
    for (int i = 0; i < 64; ++i) v[i] = 0;
#pragma unroll
    for (int kh = 0; kh < 4; ++kh) {
        int ih = 2 * oh - 1 + kh; if ((unsigned)ih >= 256u) continue;
#pragma unroll
        for (int kw = 0; kw < 4; ++kw) {
            int iw = 2 * ow - 1 + kw; if ((unsigned)iw >= 256u) continue;
#pragma unroll
            for (int ci = 0; ci < 3; ++ci)
                v[(kh * 4 + kw) * 3 + ci] =
                    f2bf(x[(((long)n * 3 + ci) * 256 + ih) * 256 + iw]);
        }
    }
    uint4* dst = (uint4*)(a0 + (long)pos * 64);
    const uint4* src = (const uint4*)v;
#pragma unroll
    for (int i = 0; i < 8; ++i) dst[i] = src[i];
}

// --- emb row norms
__global__ void embsq_kernel(const float* __restrict__ emb, float* __restrict__ esq) {
    int k = blockIdx.x, lane = threadIdx.x;
    float s = 0.f;
    for (int d = lane; d < 256; d += 64) { float v = emb[k * 256 + d]; s += v * v; }
    for (int o = 32; o; o >>= 1) s += __shfl_down(s, o, 64);
    if (lane == 0) esq[k] = s;
}

// --- emb transpose
__global__ void embT_kernel(const float* __restrict__ emb, float* __restrict__ embT) {
    int i = blockIdx.x * blockDim.x + threadIdx.x;
    if (i < 512 * 256) { int k = i >> 8; int d = i & 255; embT[d * 512 + k] = emb[i]; }
}

// ---------------------------------------------------------------------------
// MFMA implicit GEMM (same as R1). C[MxN] = A[MxK]*B[KxN].
// ---------------------------------------------------------------------------
template<int BM, int BN, int WM, int WN, bool TR, bool RELU, bool OUTF32>
__global__ __launch_bounds__(256) void igemm_kernel(
    const bfraw* __restrict__ in, const bfraw* __restrict__ wt,
    const float* __restrict__ bias, void* __restrict__ outv,
    const bfraw* __restrict__ zp,
    int Hin, int Win, int Cin, int sf, int NTW, int Ksteps,
    int lw, int lh, int N, int KW, int pad, int py, int px,
    unsigned long long pack)
{
    constexpr int APASS = BM / 64, BPASS = BN / 64;
    __shared__ __align__(16) bfraw ldsA[BM * 32];
    __shared__ __align__(16) bfraw ldsB[BN * 32];
    const int tid = threadIdx.x, lane = tid & 63, wv = tid >> 6;
    const int wm = wv / WN, wn = wv % WN;
    const int lrow = lane >> 2, lkof = (lane & 3) * 8;
    const int blockM = blockIdx.x, n0 = blockIdx.y * BN;
    const int Wm1 = (1 << lw) - 1, Hm1 = (1 << lh) - 1;

    long baseA[APASS]; int ihb[APASS], iwb[APASS];
#pragma unroll
    for (int p = 0; p < APASS; ++p) {
        int m = p * 64 + wv * 16 + lrow;
        int pos = blockM * BM + m;
        int ow = pos & Wm1; int t = pos >> lw;
        int oh = t & Hm1;   int nb = t >> lh;
        ihb[p] = oh * sf; iwb[p] = ow * sf;
        baseA[p] = ((long)(nb * Hin + ihb[p]) * Win + iwb[p]) * (long)Cin + lkof;
    }
    long baseB[BPASS];
#pragma unroll
    for (int p = 0; p < BPASS; ++p) {
        int nl = p * 64 + wv * 16 + lrow;
        baseB[p] = (long)(n0 + nl) * ((long)NTW * Cin) + lkof;
    }

    f32x4 acc[4][4];
#pragma unroll
    for (int i = 0; i < 4; ++i)
#pragma unroll
        for (int j = 0; j < 4; ++j) acc[i][j] = (f32x4)0.f;

    int ci0 = 0, tslot = 0, dy, dx, wk;
    if (TR) {
        unsigned e = (unsigned)pack & 0xFFFFu;
        dy = (int)((e >> 8) & 3) - 1; dx = (int)((e >> 4) & 3) - 1; wk = (int)(e & 15u);
    } else { dy = -pad; dx = -pad; wk = 0; }

    const int quad = lane >> 4, r16 = lane & 15;

    for (int ks = 0; ks < Ksteps; ++ks) {
        long offA = ((long)(dy * Win + dx)) * Cin + ci0;
        long offB = (long)wk * Cin + ci0;
#pragma unroll
        for (int p = 0; p < APASS; ++p) {
            int ih = ihb[p] + dy, iw = iwb[p] + dx;
            bool ok = ((unsigned)ih < (unsigned)Hin) & ((unsigned)iw < (unsigned)Win);
            const bfraw* g = ok ? (in + baseA[p] + offA) : (zp + lkof);
            gl_lds16(g, &ldsA[(p * 64 + wv * 16) * 32]);
        }
#pragma unroll
        for (int p = 0; p < BPASS; ++p)
            gl_lds16(wt + baseB[p] + offB, &ldsB[(p * 64 + wv * 16) * 32]);
        __syncthreads();
        s16x8 af[4], bf[4];
#pragma unroll
        for (int i = 0; i < 4; ++i)
            af[i] = *(const s16x8*)&ldsA[(wm * 64 + i * 16 + r16) * 32 + quad * 8];
#pragma unroll
        for (int j = 0; j < 4; ++j)
            bf[j] = *(const s16x8*)&ldsB[(wn * 64 + j * 16 + r16) * 32 + quad * 8];
#pragma unroll
        for (int i = 0; i < 4; ++i)
#pragma unroll
            for (int j = 0; j < 4; ++j)
                acc[i][j] = __builtin_amdgcn_mfma_f32_16x16x32_bf16(af[i], bf[j], acc[i][j], 0, 0, 0);
        __syncthreads();
        ci0 += 32;
        if (ci0 == Cin) {
            ci0 = 0; ++tslot;
            if (TR) {
                unsigned e = (unsigned)(pack >> (tslot * 16)) & 0xFFFFu;
                dy = (int)((e >> 8) & 3) - 1; dx = (int)((e >> 4) & 3) - 1; wk = (int)(e & 15u);
            } else { ++wk; ++dx; if (dx == KW - pad) { dx = -pad; ++dy; } }
        }
    }

#pragma unroll
    for (int j = 0; j < 4; ++j) {
        int col = wn * 64 + j * 16 + r16; int ng = n0 + col;
        float bv = bias[ng];
#pragma unroll
        for (int i = 0; i < 4; ++i) {
            int mb = wm * 64 + i * 16 + quad * 4;
#pragma unroll
            for (int r = 0; r < 4; ++r) {
                int pos2 = blockM * BM + mb + r;
                long oaddr;
                if (TR) {
                    int ow2 = pos2 & Wm1; int t = pos2 >> lw;
                    int oh2 = t & Hm1;    int nb = t >> lh;
                    int oh = 2 * oh2 + py, ow = 2 * ow2 + px;
                    oaddr = ((long)(((nb << (lh + 1)) + oh) << (lw + 1)) + ow) * N + ng;
                } else {
                    oaddr = (long)pos2 * N + ng;
                }
                float v = acc[i][j][r] + bv;
                if (RELU) v = fmaxf(v, 0.f);
                if (OUTF32) ((float*)outv)[oaddr] = v;
                else        ((bfraw*)outv)[oaddr] = f2bf(v);
            }
        }
    }
}

// --- dec2: convT k3 s1 p1, 64->3ch, 16x16 spatial tiles, 16B loads, 6-acc ILP
__global__ __launch_bounds__(256) void dec2_kernel(
    const bfraw* __restrict__ in, const float* __restrict__ wt,
    const float* __restrict__ bias, float* __restrict__ out) {
    int b = blockIdx.x;
    int n = b >> 8, ty = (b >> 4) & 15, tx = b & 15;
    int oh = ty * 16 + (threadIdx.x >> 4);
    int ow = tx * 16 + (threadIdx.x & 15);
    float a0 = bias[0], a1 = bias[1], a2 = bias[2];
    float b0 = 0.f, b1 = 0.f, b2 = 0.f;
    for (int kh = 0; kh < 3; ++kh) {
        int ih = oh + 1 - kh; if ((unsigned)ih >= 256u) continue;
        for (int kw = 0; kw < 3; ++kw) {
            int iw = ow + 1 - kw; if ((unsigned)iw >= 256u) continue;
            const bfraw* ip = in + ((long)((n * 256 + ih) * 256 + iw)) * 64;
            const float* wp = wt + (kh * 3 + kw) * 192;
#pragma unroll
            for (int c8 = 0; c8 < 8; ++c8) {
                uint4 u = *(const uint4*)(ip + c8 * 8);
                const float* w0 = wp + c8 * 24;
                float v0 = bflo(u.x), v1 = bfhi(u.x);
                float v2 = bflo(u.y), v3 = bfhi(u.y);
                float v4 = bflo(u.z), v5 = bfhi(u.z);
                float v6 = bflo(u.w), v7 = bfhi(u.w);
                a0 = fmaf(v0, w0[0],  a0); a1 = fmaf(v0, w0[1],  a1); a2 = fmaf(v0, w0[2],  a2);
                b0 = fmaf(v1, w0[3],  b0); b1 = fmaf(v1, w0[4],  b1); b2 = fmaf(v1, w0[5],  b2);
                a0 = fmaf(v2, w0[6],  a0); a1 = fmaf(v2, w0[7],  a1); a2 = fmaf(v2, w0[8],  a2);
                b0 = fmaf(v3, w0[9],  b0); b1 = fmaf(v3, w0[10], b1); b2 = fmaf(v3, w0[11], b2);
                a0 = fmaf(v4, w0[12], a0); a1 = fmaf(v4, w0[13], a1); a2 = fmaf(v4, w0[14], a2);
                b0 = fmaf(v5, w0[15], b0); b1 = fmaf(v5, w0[16], b1); b2 = fmaf(v5, w0[17], b2);
                a0 = fmaf(v6, w0[18], a0); a1 = fmaf(v6, w0[19], a1); a2 = fmaf(v6, w0[20], a2);
                b0 = fmaf(v7, w0[21], b0); b1 = fmaf(v7, w0[22], b1); b2 = fmaf(v7, w0[23], b2);
            }
        }
    }
    a0 += b0; a1 += b1; a2 += b2;
    long sp = (long)n * 3 * 65536; long hw = oh * 256 + ow;
    out[sp + hw] = a0; out[sp + 65536 + hw] = a1; out[sp + 131072 + hw] = a2;
}

// --- VQ: argmin_k(||e||^2 - 2 z.e); emits fp32 z_q (d_out) + bf16 z_q (ws)
__global__ __launch_bounds__(256) void vq_kernel(
    const float* __restrict__ ze, const float* __restrict__ emb,
    const float* __restrict__ embT, const float* __restrict__ esq,
    float* __restrict__ zq, bfraw* __restrict__ zqb, int* __restrict__ hist) {
    __shared__ int sIdx[32];
    int tid = threadIdx.x, lane = tid & 63, wv = tid >> 6;
    int posBase = blockIdx.x * 32 + wv * 8;
    float acc[8][8];
#pragma unroll
    for (int p = 0; p < 8; ++p)
#pragma unroll
        for (int j = 0; j < 8; ++j) acc[p][j] = 0.f;
    const float* zp = ze + (long)posBase * 256;
    for (int d = 0; d < 256; ++d) {
        float zs[8];
#pragma unroll
        for (int p = 0; p < 8; ++p) zs[p] = zp[p * 256 + d];
        const float* ep = embT + d * 512 + lane;
#pragma unroll
        for (int j = 0; j < 8; ++j) {
            float ev = ep[j * 64];
#pragma unroll
            for (int p = 0; p < 8; ++p) acc[p][j] = fmaf(ev, zs[p], acc[p][j]);
        }
    }
#pragma unroll
    for (int p = 0; p < 8; ++p) {
        float best = 1e30f; int bk = 0;
#pragma unroll
        for (int j = 0; j < 8; ++j) {
            int k = j * 64 + lane;
            float dist = esq[k] - 2.f * acc[p][j];
            if (dist < best) { best = dist; bk = k; }
        }
        for (int off = 32; off; off >>= 1) {
            float ov = __shfl_down(best, off, 64);
            int   ok = __shfl_down(bk,   off, 64);
            if (ov < best || (ov == best && ok < bk)) { best = ov; bk = ok; }
        }
        if (lane == 0) { sIdx[wv * 8 + p] = bk; atomicAdd(&hist[bk], 1); }
    }
    __syncthreads();
    long blockPos = (long)blockIdx.x * 32;
    const float4* emb4 = (const float4*)emb;
    float4*  zq4  = (float4*)(zq + blockPos * 256);
    ushort4* zqb4 = (ushort4*)(zqb + blockPos * 256);
    for (int i = tid; i < 32 * 64; i += 256) {
        int p = i >> 6, c = i & 63;
        float4 v = emb4[sIdx[p] * 64 + c];
        zq4[i] = v;
        ushort4 u; u.x = f2bf(v.x); u.y = f2bf(v.y); u.z = f2bf(v.z); u.w = f2bf(v.w);
        zqb4[i] = u;
    }
}

// --- perplexity
__global__ void ppl_kernel(const int* __restrict__ hist, float* __restrict__ outp) {
    __shared__ float red[512];
    int t = threadIdx.x;
    float p = (float)hist[t] * (1.0f / 65536.0f);
    red[t] = p * logf(p + 1e-10f);
    __syncthreads();
    for (int s = 256; s; s >>= 1) { if (t < s) red[t] += red[t + s]; __syncthreads(); }
    if (t == 0) *outp = expf(-red[0]);
}

// host: pack convT parity-class tap table (4 entries x 16 bits)
static unsigned long long packFor(int py, int px) {
    unsigned long long pk = 0; int s = 0;
    for (int kh = 0; kh < 4; ++kh) {
        if (((py + 1 - kh) & 1) != 0) continue;
        int dy = (py + 1 - kh) / 2;
        for (int kw = 0; kw < 4; ++kw) {
            if (((px + 1 - kw) & 1) != 0) continue;
            int dx = (px + 1 - kw) / 2;
            unsigned e = ((unsigned)(dy + 1) << 8) | ((unsigned)(dx + 1) << 4) | (unsigned)(kh * 4 + kw);
            pk |= (unsigned long long)e << (16 * s); ++s;
        }
    }
    return pk;
}

extern "C" void kernel_launch(void* const* d_in, const int* in_sizes, int n_in,
                              void* d_out, int out_size, void* d_ws, size_t ws_size,
                              hipStream_t stream) {
    const float* x       = (const float*)d_in[0];
    const float* w_enc1  = (const float*)d_in[1];
    const float* b_enc1  = (const float*)d_in[2];
    const float* w_enc2  = (const float*)d_in[3];
    const float* b_enc2  = (const float*)d_in[4];
    const float* w_prevq = (const float*)d_in[5];
    const float* b_prevq = (const float*)d_in[6];
    const float* emb     = (const float*)d_in[7];
    const float* w_post  = (const float*)d_in[8];
    const float* b_post  = (const float*)d_in[9];
    const float* w_dec1  = (const float*)d_in[10];
    const float* b_dec1  = (const float*)d_in[11];
    const float* w_dec2  = (const float*)d_in[12];
    const float* b_dec2  = (const float*)d_in[13];

    float* out = (float*)d_out;
    float* xr  = out;                     // 3,145,728
    float* ze  = out + 3145728;           // 16,777,216
    float* zq  = ze + 16777216;           // 16,777,216
    float* ppl = zq + 16777216;           // 1

    // ---- workspace carve (bytes) ----
    char* W = (char*)d_ws;
    float* wd2t = (float*)(W + 16384);      // dec2 fp32 [tap][ci][co]    7 KB
    float* esq  = (float*)(W + 24576);      // 2 KB
    float* embT = (float*)(W + 32768);      // 512 KB
    int*   hist = (int*)(W + 557056);       // 2 KB
    bfraw* zp   = (bfraw*)(W + 559360);     // zero page, 256 B
    bfraw* w2b  = (bfraw*)(W + 560128);     // enc2  bf16 [co][16][64]   256 KB
    bfraw* w3b  = (bfraw*)(W + 822272);     // prevq bf16 [co][9][128]   576 KB
    bfraw* wpb  = (bfraw*)(W + 1412096);    // post  bf16 [co][16][256]  1 MB
    bfraw* wd1b = (bfraw*)(W + 2460672);    // dec1  bf16 [co][16][128]  256 KB
    bfraw* wb1  = (bfraw*)(W + 2722816);    // enc1  bf16 [co][64]        8 KB
    // bufX (134.2 MB): A0 -> h2 -> zqb -> ddec1 (sequential lifetimes)
    bfraw* bufX = (bfraw*)(W + 4194304);
    bfraw* a0    = bufX;                    // 16.8M elems (enc1 im2col)
    bfraw* h2    = bufX;                    // 8.4M elems (enc2 out)
    bfraw* zqb   = bufX;                    // 16.8M elems (z_q bf16)
    bfraw* ddec1 = bufX;                    // 67.1M elems (dec1 out)
    // bufY (67.1 MB): dpost
    bfraw* dpost = (bfraw*)(W + 138412032);
    bfraw* h1    = (bfraw*)ze;              // alias: h1 dies before prevq writes z_e

    // ---- weight transforms + precomputes ----
    wt_kernel<<<8, 256, 0, stream>>>(w_dec2, wd2t, 3, 64, 3, 3, 1);
    wb1_kernel<<<16, 256, 0, stream>>>(w_enc1, wb1);
    wtb_kernel<<<512, 256, 0, stream>>>(w_enc2, w2b, 128, 64, 4, 4, 0);
    wtb_kernel<<<1152, 256, 0, stream>>>(w_prevq, w3b, 256, 128, 3, 3, 0);
    wtb_kernel<<<2048, 256, 0, stream>>>(w_post, wpb, 128, 256, 4, 4, 1);
    wtb_kernel<<<512, 256, 0, stream>>>(w_dec1, wd1b, 64, 128, 4, 4, 1);
    embsq_kernel<<<512, 64, 0, stream>>>(emb, esq);
    embT_kernel<<<512, 256, 0, stream>>>(emb, embT);
    hipMemsetAsync(hist, 0, 512 * sizeof(int), stream);
    hipMemsetAsync(zp, 0, 256, stream);

    // ---- encoder ----
    xpack_kernel<<<1024, 256, 0, stream>>>(x, a0);
    // enc1 as plain GEMM over im2col'd A0: M=262144 (one 512x512 "image"),
    // K=64 (48 real), N=64, 1x1 conv semantics.
    igemm_kernel<256, 64, 4, 1, false, true, false><<<dim3(1024, 1), 256, 0, stream>>>(
        a0, wb1, b_enc1, h1, zp, 512, 512, 64, 1, 1, 2, 9, 9, 64, 1, 0, 0, 0, 0ULL);
    // enc2: M=65536,K=16*64,N=128
    igemm_kernel<128, 128, 2, 2, false, true, false><<<dim3(512, 1), 256, 0, stream>>>(
        h1, w2b, b_enc2, h2, zp, 128, 128, 64, 2, 16, 32, 6, 6, 128, 4, 1, 0, 0, 0ULL);
    // prevq: M=65536,K=9*128,N=256 -> ze fp32
    igemm_kernel<128, 128, 2, 2, false, false, true><<<dim3(512, 2), 256, 0, stream>>>(
        h2, w3b, b_prevq, ze, zp, 64, 64, 128, 1, 9, 36, 6, 6, 256, 3, 1, 0, 0, 0ULL);

    // ---- VQ ----
    vq_kernel<<<2048, 256, 0, stream>>>(ze, emb, embT, esq, zq, zqb, hist);
    ppl_kernel<<<1, 512, 0, stream>>>(hist, ppl);

    // ---- decoder ----
    for (int cls = 0; cls < 4; ++cls) {
        int py = cls >> 1, px = cls & 1;
        igemm_kernel<128, 128, 2, 2, true, false, false><<<dim3(512, 1), 256, 0, stream>>>(
            zqb, wpb, b_post, dpost, zp, 64, 64, 256, 1, 16, 32, 6, 6, 128, 4, 1,
            py, px, packFor(py, px));
    }
    for (int cls = 0; cls < 4; ++cls) {
        int py = cls >> 1, px = cls & 1;
        igemm_kernel<256, 64, 4, 1, true, true, false><<<dim3(1024, 1), 256, 0, stream>>>(
            dpost, wd1b, b_dec1, ddec1, zp, 128, 128, 128, 1, 16, 16, 7, 7, 64, 4, 1,
            py, px, packFor(py, px));
    }
    dec2_kernel<<<4096, 256, 0, stream>>>(ddec1, wd2t, b_dec2, xr);
}

// Round 5
// 1023.504 us; speedup vs baseline: 22.5623x; 1.2195x over previous
//
#include <hip/hip_runtime.h>
#include <stdint.h>

// ---------------------------------------------------------------------------
// VQ-VAE forward on MI355X. Round 4: fix vqm argmin cross-wave race (two
// waves cover the same rows over different code halves; now merged via LDS
// before the single hist atomic + sIdx write). Rest identical to R3.
// ---------------------------------------------------------------------------

typedef unsigned short bfraw;
typedef __attribute__((ext_vector_type(8))) short s16x8;
typedef __attribute__((ext_vector_type(4))) float f32x4;

__device__ __forceinline__ float bflo(unsigned int u) {
    union { unsigned int i; float f; } v; v.i = u << 16; return v.f;
}
__device__ __forceinline__ float bfhi(unsigned int u) {
    union { unsigned int i; float f; } v; v.i = u & 0xFFFF0000u; return v.f;
}
__device__ __forceinline__ bfraw f2bf(float f) {
    union { float f; unsigned int i; } v; v.f = f;
    unsigned int r = v.i + 0x7FFFu + ((v.i >> 16) & 1u);   // RNE
    return (bfraw)(r >> 16);
}

// async 16B global->LDS. LDS dest: wave-uniform base + lane*16.
__device__ __forceinline__ void gl_lds16(const void* g, void* l) {
    auto gp = reinterpret_cast<const __attribute__((address_space(1))) unsigned int*>(
        reinterpret_cast<uintptr_t>(g));
    auto lp = reinterpret_cast<__attribute__((address_space(3))) unsigned int*>(
        reinterpret_cast<uintptr_t>(l));
    __builtin_amdgcn_global_load_lds(gp, lp, 16, 0, 0);
}

// --- weight transform (fp32, [tap][ci][co]) for dec2
__global__ void wt_kernel(const float* __restrict__ w, float* __restrict__ wt,
                          int Cout, int Cin, int KH, int KW, int transposed) {
    int n = Cout * Cin * KH * KW;
    for (int i = blockIdx.x * blockDim.x + threadIdx.x; i < n; i += gridDim.x * blockDim.x) {
        int co = i % Cout; int t = i / Cout;
        int ci = t % Cin;  int tap = t / Cin;
        int kw = tap % KW; int kh = tap / KW;
        float v = transposed ? w[(((long)ci * Cout + co) * KH + kh) * KW + kw]
                             : w[(((long)co * Cin + ci) * KH + kh) * KW + kw];
        wt[i] = v;
    }
}

// --- weight transform (bf16, [co][tap][ci]) for MFMA convs (B as [n][k]);
//     with KH=KW=1 also converts emb[512][256] to bf16 B layout.
__global__ void wtb_kernel(const float* __restrict__ w, bfraw* __restrict__ wt,
                           int Cout, int Cin, int KH, int KW, int transposed) {
    int n = Cout * Cin * KH * KW;
    int NT = KH * KW;
    for (int i = blockIdx.x * blockDim.x + threadIdx.x; i < n; i += gridDim.x * blockDim.x) {
        int ci = i % Cin; int t = i / Cin;
        int tap = t % NT; int co = t / NT;
        int kh = tap / KW, kw = tap % KW;
        float v = transposed ? w[(((long)ci * Cout + co) * KH + kh) * KW + kw]
                             : w[(((long)co * Cin + ci) * KH + kh) * KW + kw];
        wt[i] = f2bf(v);
    }
}

// --- enc1 weight pack: wb1[co][k64], k=(kh*4+kw)*3+ci (48 real, 16 zero)
__global__ void wb1_kernel(const float* __restrict__ w, bfraw* __restrict__ wt) {
    int i = blockIdx.x * 256 + threadIdx.x;
    if (i >= 4096) return;
    int k = i & 63, co = i >> 6;
    bfraw v = 0;
    if (k < 48) {
        int ci = k % 3, tap = k / 3, kh = tap >> 2, kw = tap & 3;
        v = f2bf(w[(((long)co * 3 + ci) * 4 + kh) * 4 + kw]);
    }
    wt[(long)co * 64 + k] = v;
}

// --- enc1 im2col: x NCHW fp32 -> A0[pos][64] bf16 (48 patch vals + 16 zeros)
__global__ __launch_bounds__(256) void xpack_kernel(const float* __restrict__ x,
                                                    bfraw* __restrict__ a0) {
    int pos = blockIdx.x * 256 + threadIdx.x;        // 262144
    int ow = pos & 127, oh = (pos >> 7) & 127, n = pos >> 14;
    __align__(16) bfraw v[64];
#pragma unroll
    for (int i = 0; i < 64; ++i) v[i] = 0;
#pragma unroll
    for (int kh = 0; kh < 4; ++kh) {
        int ih = 2 * oh - 1 + kh; if ((unsigned)ih >= 256u) continue;
#pragma unroll
        for (int kw = 0; kw < 4; ++kw) {
            int iw = 2 * ow - 1 + kw; if ((unsigned)iw >= 256u) continue;
#pragma unroll
            for (int ci = 0; ci < 3; ++ci)
                v[(kh * 4 + kw) * 3 + ci] =
                    f2bf(x[(((long)n * 3 + ci) * 256 + ih) * 256 + iw]);
        }
    }
    uint4* dst = (uint4*)(a0 + (long)pos * 64);
    const uint4* src = (const uint4*)v;
#pragma unroll
    for (int i = 0; i < 8; ++i) dst[i] = src[i];
}

// --- emb row norms
__global__ void embsq_kernel(const float* __restrict__ emb, float* __restrict__ esq) {
    int k = blockIdx.x, lane = threadIdx.x;
    float s = 0.f;
    for (int d = lane; d < 256; d += 64) { float v = emb[k * 256 + d]; s += v * v; }
    for (int o = 32; o; o >>= 1) s += __shfl_down(s, o, 64);
    if (lane == 0) esq[k] = s;
}

// ---------------------------------------------------------------------------
// MFMA implicit GEMM. C[MxN] = A[MxK]*B[KxN].
// ---------------------------------------------------------------------------
template<int BM, int BN, int WM, int WN, bool TR, bool RELU, bool OUTF32, bool DUALB>
__global__ __launch_bounds__(256) void igemm_kernel(
    const bfraw* __restrict__ in, const bfraw* __restrict__ wt,
    const float* __restrict__ bias, void* __restrict__ outv,
    bfraw* __restrict__ outb, const bfraw* __restrict__ zp,
    int Hin, int Win, int Cin, int sf, int NTW, int Ksteps,
    int lw, int lh, int N, int KW, int pad, int py, int px,
    unsigned long long pack)
{
    constexpr int APASS = BM / 64, BPASS = BN / 64;
    __shared__ __align__(16) bfraw ldsA[BM * 32];
    __shared__ __align__(16) bfraw ldsB[BN * 32];
    const int tid = threadIdx.x, lane = tid & 63, wv = tid >> 6;
    const int wm = wv / WN, wn = wv % WN;
    const int lrow = lane >> 2, lkof = (lane & 3) * 8;
    const int blockM = blockIdx.x, n0 = blockIdx.y * BN;
    const int Wm1 = (1 << lw) - 1, Hm1 = (1 << lh) - 1;

    long baseA[APASS]; int ihb[APASS], iwb[APASS];
#pragma unroll
    for (int p = 0; p < APASS; ++p) {
        int m = p * 64 + wv * 16 + lrow;
        int pos = blockM * BM + m;
        int ow = pos & Wm1; int t = pos >> lw;
        int oh = t & Hm1;   int nb = t >> lh;
        ihb[p] = oh * sf; iwb[p] = ow * sf;
        baseA[p] = ((long)(nb * Hin + ihb[p]) * Win + iwb[p]) * (long)Cin + lkof;
    }
    long baseB[BPASS];
#pragma unroll
    for (int p = 0; p < BPASS; ++p) {
        int nl = p * 64 + wv * 16 + lrow;
        baseB[p] = (long)(n0 + nl) * ((long)NTW * Cin) + lkof;
    }

    f32x4 acc[4][4];
#pragma unroll
    for (int i = 0; i < 4; ++i)
#pragma unroll
        for (int j = 0; j < 4; ++j) acc[i][j] = (f32x4)0.f;

    int ci0 = 0, tslot = 0, dy, dx, wk;
    if (TR) {
        unsigned e = (unsigned)pack & 0xFFFFu;
        dy = (int)((e >> 8) & 3) - 1; dx = (int)((e >> 4) & 3) - 1; wk = (int)(e & 15u);
    } else { dy = -pad; dx = -pad; wk = 0; }

    const int quad = lane >> 4, r16 = lane & 15;

    for (int ks = 0; ks < Ksteps; ++ks) {
        long offA = ((long)(dy * Win + dx)) * Cin + ci0;
        long offB = (long)wk * Cin + ci0;
#pragma unroll
        for (int p = 0; p < APASS; ++p) {
            int ih = ihb[p] + dy, iw = iwb[p] + dx;
            bool ok = ((unsigned)ih < (unsigned)Hin) & ((unsigned)iw < (unsigned)Win);
            const bfraw* g = ok ? (in + baseA[p] + offA) : (zp + lkof);
            gl_lds16(g, &ldsA[(p * 64 + wv * 16) * 32]);
        }
#pragma unroll
        for (int p = 0; p < BPASS; ++p)
            gl_lds16(wt + baseB[p] + offB, &ldsB[(p * 64 + wv * 16) * 32]);
        __syncthreads();
        s16x8 af[4], bf[4];
#pragma unroll
        for (int i = 0; i < 4; ++i)
            af[i] = *(const s16x8*)&ldsA[(wm * 64 + i * 16 + r16) * 32 + quad * 8];
#pragma unroll
        for (int j = 0; j < 4; ++j)
            bf[j] = *(const s16x8*)&ldsB[(wn * 64 + j * 16 + r16) * 32 + quad * 8];
#pragma unroll
        for (int i = 0; i < 4; ++i)
#pragma unroll
            for (int j = 0; j < 4; ++j)
                acc[i][j] = __builtin_amdgcn_mfma_f32_16x16x32_bf16(af[i], bf[j], acc[i][j], 0, 0, 0);
        __syncthreads();
        ci0 += 32;
        if (ci0 == Cin) {
            ci0 = 0; ++tslot;
            if (TR) {
                unsigned e = (unsigned)(pack >> (tslot * 16)) & 0xFFFFu;
                dy = (int)((e >> 8) & 3) - 1; dx = (int)((e >> 4) & 3) - 1; wk = (int)(e & 15u);
            } else { ++wk; ++dx; if (dx == KW - pad) { dx = -pad; ++dy; } }
        }
    }

#pragma unroll
    for (int j = 0; j < 4; ++j) {
        int col = wn * 64 + j * 16 + r16; int ng = n0 + col;
        float bv = bias[ng];
#pragma unroll
        for (int i = 0; i < 4; ++i) {
            int mb = wm * 64 + i * 16 + quad * 4;
#pragma unroll
            for (int r = 0; r < 4; ++r) {
                int pos2 = blockM * BM + mb + r;
                long oaddr;
                if (TR) {
                    int ow2 = pos2 & Wm1; int t = pos2 >> lw;
                    int oh2 = t & Hm1;    int nb = t >> lh;
                    int oh = 2 * oh2 + py, ow = 2 * ow2 + px;
                    oaddr = ((long)(((nb << (lh + 1)) + oh) << (lw + 1)) + ow) * N + ng;
                } else {
                    oaddr = (long)pos2 * N + ng;
                }
                float v = acc[i][j][r] + bv;
                if (RELU) v = fmaxf(v, 0.f);
                if (OUTF32) {
                    ((float*)outv)[oaddr] = v;
                    if (DUALB) outb[oaddr] = f2bf(v);
                } else {
                    ((bfraw*)outv)[oaddr] = f2bf(v);
                }
            }
        }
    }
}

// --- dec2: convT k3 s1 p1, 64->3ch, 16x16 spatial tiles, 16B loads, 6-acc ILP
__global__ __launch_bounds__(256) void dec2_kernel(
    const bfraw* __restrict__ in, const float* __restrict__ wt,
    const float* __restrict__ bias, float* __restrict__ out) {
    int b = blockIdx.x;
    int n = b >> 8, ty = (b >> 4) & 15, tx = b & 15;
    int oh = ty * 16 + (threadIdx.x >> 4);
    int ow = tx * 16 + (threadIdx.x & 15);
    float a0 = bias[0], a1 = bias[1], a2 = bias[2];
    float b0 = 0.f, b1 = 0.f, b2 = 0.f;
    for (int kh = 0; kh < 3; ++kh) {
        int ih = oh + 1 - kh; if ((unsigned)ih >= 256u) continue;
        for (int kw = 0; kw < 3; ++kw) {
            int iw = ow + 1 - kw; if ((unsigned)iw >= 256u) continue;
            const bfraw* ip = in + ((long)((n * 256 + ih) * 256 + iw)) * 64;
            const float* wp = wt + (kh * 3 + kw) * 192;
#pragma unroll
            for (int c8 = 0; c8 < 8; ++c8) {
                uint4 u = *(const uint4*)(ip + c8 * 8);
                const float* w0 = wp + c8 * 24;
                float v0 = bflo(u.x), v1 = bfhi(u.x);
                float v2 = bflo(u.y), v3 = bfhi(u.y);
                float v4 = bflo(u.z), v5 = bfhi(u.z);
                float v6 = bflo(u.w), v7 = bfhi(u.w);
                a0 = fmaf(v0, w0[0],  a0); a1 = fmaf(v0, w0[1],  a1); a2 = fmaf(v0, w0[2],  a2);
                b0 = fmaf(v1, w0[3],  b0); b1 = fmaf(v1, w0[4],  b1); b2 = fmaf(v1, w0[5],  b2);
                a0 = fmaf(v2, w0[6],  a0); a1 = fmaf(v2, w0[7],  a1); a2 = fmaf(v2, w0[8],  a2);
                b0 = fmaf(v3, w0[9],  b0); b1 = fmaf(v3, w0[10], b1); b2 = fmaf(v3, w0[11], b2);
                a0 = fmaf(v4, w0[12], a0); a1 = fmaf(v4, w0[13], a1); a2 = fmaf(v4, w0[14], a2);
                b0 = fmaf(v5, w0[15], b0); b1 = fmaf(v5, w0[16], b1); b2 = fmaf(v5, w0[17], b2);
                a0 = fmaf(v6, w0[18], a0); a1 = fmaf(v6, w0[19], a1); a2 = fmaf(v6, w0[20], a2);
                b0 = fmaf(v7, w0[21], b0); b1 = fmaf(v7, w0[22], b1); b2 = fmaf(v7, w0[23], b2);
            }
        }
    }
    a0 += b0; a1 += b1; a2 += b2;
    long sp = (long)n * 3 * 65536; long hw = oh * 256 + ow;
    out[sp + hw] = a0; out[sp + 65536 + hw] = a1; out[sp + 131072 + hw] = a2;
}

// ---------------------------------------------------------------------------
// VQ via MFMA: S = Zb[128 x 256] x EbT (codes as B rows), dist = ||e||^2 - 2S.
// Two waves share each 64-row group (different code halves): partial argmins
// are merged via LDS before ONE sIdx write + ONE hist atomic per row.
// ---------------------------------------------------------------------------
__global__ __launch_bounds__(256) void vqm_kernel(
    const bfraw* __restrict__ zeb, const bfraw* __restrict__ embB,
    const float* __restrict__ esq, const float* __restrict__ emb,
    float* __restrict__ zq, bfraw* __restrict__ zqb, int* __restrict__ hist)
{
    __shared__ __align__(16) bfraw ldsA[128 * 32];
    __shared__ __align__(16) bfraw ldsB[128 * 32];
    __shared__ float sEsq[512];
    __shared__ float sVal[2][128];
    __shared__ int   sKey[2][128];
    __shared__ int   sIdx[128];
    const int tid = threadIdx.x, lane = tid & 63, wv = tid >> 6;
    const int wm = wv >> 1, wn = wv & 1;
    const int lrow = lane >> 2, lkof = (lane & 3) * 8;
    const int quad = lane >> 4, r16 = lane & 15;
    const int posBase = blockIdx.x * 128;

    for (int i = tid; i < 512; i += 256) sEsq[i] = esq[i];

    const long baseA0 = (long)(posBase + wv * 16 + lrow) * 256 + lkof;
    const long baseA1 = baseA0 + 64 * 256;

    float bestv[16]; int bestk[16];
#pragma unroll
    for (int t = 0; t < 16; ++t) { bestv[t] = 1e30f; bestk[t] = 1 << 30; }

    for (int chunk = 0; chunk < 4; ++chunk) {
        f32x4 acc[4][4];
#pragma unroll
        for (int i = 0; i < 4; ++i)
#pragma unroll
            for (int j = 0; j < 4; ++j) acc[i][j] = (f32x4)0.f;
        const long baseB0 = (long)(chunk * 128 + wv * 16 + lrow) * 256 + lkof;
        const long baseB1 = baseB0 + 64 * 256;
        for (int k = 0; k < 8; ++k) {
            gl_lds16(zeb + baseA0 + k * 32, &ldsA[(wv * 16) * 32]);
            gl_lds16(zeb + baseA1 + k * 32, &ldsA[(64 + wv * 16) * 32]);
            gl_lds16(embB + baseB0 + k * 32, &ldsB[(wv * 16) * 32]);
            gl_lds16(embB + baseB1 + k * 32, &ldsB[(64 + wv * 16) * 32]);
            __syncthreads();
            s16x8 af[4], bf[4];
#pragma unroll
            for (int i = 0; i < 4; ++i)
                af[i] = *(const s16x8*)&ldsA[(wm * 64 + i * 16 + r16) * 32 + quad * 8];
#pragma unroll
            for (int j = 0; j < 4; ++j)
                bf[j] = *(const s16x8*)&ldsB[(wn * 64 + j * 16 + r16) * 32 + quad * 8];
#pragma unroll
            for (int i = 0; i < 4; ++i)
#pragma unroll
                for (int j = 0; j < 4; ++j)
                    acc[i][j] = __builtin_amdgcn_mfma_f32_16x16x32_bf16(af[i], bf[j], acc[i][j], 0, 0, 0);
            __syncthreads();
        }
        // chunk epilogue: dist + argmin. C row = i*16 + quad*4 + r, col = r16.
#pragma unroll
        for (int i = 0; i < 4; ++i) {
#pragma unroll
            for (int r = 0; r < 4; ++r) {
                float v = 1e30f; int kk = 1 << 30;
#pragma unroll
                for (int j = 0; j < 4; ++j) {
                    int code = chunk * 128 + wn * 64 + j * 16 + r16;
                    float d = sEsq[code] - 2.f * acc[i][j][r];
                    if (d < v || (d == v && code < kk)) { v = d; kk = code; }
                }
#pragma unroll
                for (int m = 1; m < 16; m <<= 1) {
                    float ov = __shfl_xor(v, m, 64);
                    int   ok = __shfl_xor(kk, m, 64);
                    if (ov < v || (ov == v && ok < kk)) { v = ov; kk = ok; }
                }
                int s = i * 4 + r;
                if (v < bestv[s] || (v == bestv[s] && kk < bestk[s])) {
                    bestv[s] = v; bestk[s] = kk;
                }
            }
        }
    }
    // publish per-wave partials (each wave covered half the codes for its rows)
    if (r16 == 0) {
#pragma unroll
        for (int i = 0; i < 4; ++i)
#pragma unroll
            for (int r = 0; r < 4; ++r) {
                int localRow = wm * 64 + i * 16 + quad * 4 + r;
                int s = i * 4 + r;
                sVal[wn][localRow] = bestv[s];
                sKey[wn][localRow] = bestk[s];
            }
    }
    __syncthreads();
    // merge halves: one thread per row, single sIdx write + single hist atomic
    if (tid < 128) {
        float v0 = sVal[0][tid]; int k0 = sKey[0][tid];
        float v1 = sVal[1][tid]; int k1 = sKey[1][tid];
        int kk = (v1 < v0 || (v1 == v0 && k1 < k0)) ? k1 : k0;
        sIdx[tid] = kk;
        atomicAdd(&hist[kk], 1);
    }
    __syncthreads();
    const float4* emb4 = (const float4*)emb;
    float4*  zq4  = (float4*)(zq + (long)posBase * 256);
    ushort4* zqb4 = (ushort4*)(zqb + (long)posBase * 256);
    for (int i2 = tid; i2 < 128 * 64; i2 += 256) {
        int p = i2 >> 6, c = i2 & 63;
        float4 vv = emb4[sIdx[p] * 64 + c];
        zq4[i2] = vv;
        ushort4 u; u.x = f2bf(vv.x); u.y = f2bf(vv.y); u.z = f2bf(vv.z); u.w = f2bf(vv.w);
        zqb4[i2] = u;
    }
}

// --- perplexity
__global__ void ppl_kernel(const int* __restrict__ hist, float* __restrict__ outp) {
    __shared__ float red[512];
    int t = threadIdx.x;
    float p = (float)hist[t] * (1.0f / 65536.0f);
    red[t] = p * logf(p + 1e-10f);
    __syncthreads();
    for (int s = 256; s; s >>= 1) { if (t < s) red[t] += red[t + s]; __syncthreads(); }
    if (t == 0) *outp = expf(-red[0]);
}

// host: pack convT parity-class tap table (4 entries x 16 bits)
static unsigned long long packFor(int py, int px) {
    unsigned long long pk = 0; int s = 0;
    for (int kh = 0; kh < 4; ++kh) {
        if (((py + 1 - kh) & 1) != 0) continue;
        int dy = (py + 1 - kh) / 2;
        for (int kw = 0; kw < 4; ++kw) {
            if (((px + 1 - kw) & 1) != 0) continue;
            int dx = (px + 1 - kw) / 2;
            unsigned e = ((unsigned)(dy + 1) << 8) | ((unsigned)(dx + 1) << 4) | (unsigned)(kh * 4 + kw);
            pk |= (unsigned long long)e << (16 * s); ++s;
        }
    }
    return pk;
}

extern "C" void kernel_launch(void* const* d_in, const int* in_sizes, int n_in,
                              void* d_out, int out_size, void* d_ws, size_t ws_size,
                              hipStream_t stream) {
    const float* x       = (const float*)d_in[0];
    const float* w_enc1  = (const float*)d_in[1];
    const float* b_enc1  = (const float*)d_in[2];
    const float* w_enc2  = (const float*)d_in[3];
    const float* b_enc2  = (const float*)d_in[4];
    const float* w_prevq = (const float*)d_in[5];
    const float* b_prevq = (const float*)d_in[6];
    const float* emb     = (const float*)d_in[7];
    const float* w_post  = (const float*)d_in[8];
    const float* b_post  = (const float*)d_in[9];
    const float* w_dec1  = (const float*)d_in[10];
    const float* b_dec1  = (const float*)d_in[11];
    const float* w_dec2  = (const float*)d_in[12];
    const float* b_dec2  = (const float*)d_in[13];

    float* out = (float*)d_out;
    float* xr  = out;                     // 3,145,728
    float* ze  = out + 3145728;           // 16,777,216
    float* zq  = ze + 16777216;           // 16,777,216
    float* ppl = zq + 16777216;           // 1

    // ---- workspace carve (bytes) ----
    char* W = (char*)d_ws;
    float* wd2t = (float*)(W + 16384);      // dec2 fp32 [tap][ci][co]    7 KB
    float* esq  = (float*)(W + 24576);      // 2 KB
    int*   hist = (int*)(W + 28672);        // 2 KB
    bfraw* zp   = (bfraw*)(W + 32768);      // zero page, 256 B
    bfraw* w2b  = (bfraw*)(W + 560128);     // enc2  bf16 [co][16][64]   256 KB
    bfraw* w3b  = (bfraw*)(W + 822272);     // prevq bf16 [co][9][128]   576 KB
    bfraw* wpb  = (bfraw*)(W + 1412096);    // post  bf16 [co][16][256]  1 MB
    bfraw* wd1b = (bfraw*)(W + 2460672);    // dec1  bf16 [co][16][128]  256 KB
    bfraw* wb1  = (bfraw*)(W + 2722816);    // enc1  bf16 [co][64]        8 KB
    bfraw* embB = (bfraw*)(W + 2736128);    // emb   bf16 [512][256]    256 KB
    // bufX (128 MiB @ +4 MiB): sequential lifetimes
    //   a0 [0,33.5M) -> h2 [0,16.8M) -> zeb [16.8M,50.3M) -> zqb [50.3M,83.9M)
    //   -> ddec1 [0,134.2M)
    char* bufX = W + 4194304;
    bfraw* a0    = (bfraw*)bufX;
    bfraw* h2    = (bfraw*)bufX;
    bfraw* zeb   = (bfraw*)(bufX + 16777216);
    bfraw* zqb   = (bfraw*)(bufX + 50331648);
    bfraw* ddec1 = (bfraw*)bufX;
    // bufY (67.1 MB): dpost
    bfraw* dpost = (bfraw*)(W + 138412032);
    bfraw* h1    = (bfraw*)ze;              // alias: h1 dies before prevq writes z_e

    // ---- weight transforms + precomputes ----
    wt_kernel<<<8, 256, 0, stream>>>(w_dec2, wd2t, 3, 64, 3, 3, 1);
    wb1_kernel<<<16, 256, 0, stream>>>(w_enc1, wb1);
    wtb_kernel<<<512, 256, 0, stream>>>(w_enc2, w2b, 128, 64, 4, 4, 0);
    wtb_kernel<<<1152, 256, 0, stream>>>(w_prevq, w3b, 256, 128, 3, 3, 0);
    wtb_kernel<<<2048, 256, 0, stream>>>(w_post, wpb, 128, 256, 4, 4, 1);
    wtb_kernel<<<512, 256, 0, stream>>>(w_dec1, wd1b, 64, 128, 4, 4, 1);
    wtb_kernel<<<512, 256, 0, stream>>>(emb, embB, 512, 256, 1, 1, 0);
    embsq_kernel<<<512, 64, 0, stream>>>(emb, esq);
    hipMemsetAsync(hist, 0, 512 * sizeof(int), stream);
    hipMemsetAsync(zp, 0, 256, stream);

    // ---- encoder ----
    xpack_kernel<<<1024, 256, 0, stream>>>(x, a0);
    igemm_kernel<256, 64, 4, 1, false, true, false, false><<<dim3(1024, 1), 256, 0, stream>>>(
        a0, wb1, b_enc1, h1, nullptr, zp, 512, 512, 64, 1, 1, 2, 9, 9, 64, 1, 0, 0, 0, 0ULL);
    igemm_kernel<128, 128, 2, 2, false, true, false, false><<<dim3(512, 1), 256, 0, stream>>>(
        h1, w2b, b_enc2, h2, nullptr, zp, 128, 128, 64, 2, 16, 32, 6, 6, 128, 4, 1, 0, 0, 0ULL);
    // prevq: dual output ze fp32 + zeb bf16
    igemm_kernel<128, 128, 2, 2, false, false, true, true><<<dim3(512, 2), 256, 0, stream>>>(
        h2, w3b, b_prevq, ze, zeb, zp, 64, 64, 128, 1, 9, 36, 6, 6, 256, 3, 1, 0, 0, 0ULL);

    // ---- VQ (MFMA) ----
    vqm_kernel<<<512, 256, 0, stream>>>(zeb, embB, esq, emb, zq, zqb, hist);
    ppl_kernel<<<1, 512, 0, stream>>>(hist, ppl);

    // ---- decoder ----
    for (int cls = 0; cls < 4; ++cls) {
        int py = cls >> 1, px = cls & 1;
        igemm_kernel<128, 128, 2, 2, true, false, false, false><<<dim3(512, 1), 256, 0, stream>>>(
            zqb, wpb, b_post, dpost, nullptr, zp, 64, 64, 256, 1, 16, 32, 6, 6, 128, 4, 1,
            py, px, packFor(py, px));
    }
    for (int cls = 0; cls < 4; ++cls) {
        int py = cls >> 1, px = cls & 1;
        igemm_kernel<256, 64, 4, 1, true, true, false, false><<<dim3(1024, 1), 256, 0, stream>>>(
            dpost, wd1b, b_dec1, ddec1, nullptr, zp, 128, 128, 128, 1, 16, 16, 7, 7, 64, 4, 1,
            py, px, packFor(py, px));
    }
    dec2_kernel<<<4096, 256, 0, stream>>>(ddec1, wd2t, b_dec2, xr);
}